// Round 1
// 437.772 us; speedup vs baseline: 1.0791x; 1.0791x over previous
//
#include <hip/hip_runtime.h>

// Problem constants (match reference)
#define BB    32
#define HH    224
#define WW    224
#define OUTC  64
#define KK    5
#define PADP  2
#define LL    (HH * WW)            // 50176
#define GPB   (LL / 4)             // 12544 groups of 4 positions per image

__global__ __launch_bounds__(256) void gray_conv_kernel(
    const float* __restrict__ x,     // [B, 1, H, W]
    const float* __restrict__ wgt,   // [OUT, 25]
    float* __restrict__ out)         // [B, OUT, H, W]
{
    // Weights in LDS; row stride 28 floats keeps rows 16B-aligned so the
    // per-o row read is 6x ds_read_b128 + 1x ds_read_b32, all-lane broadcast
    // (zero bank conflicts). Each row is now read ONCE per o and reused for
    // 4 output positions (was: re-read per position).
    __shared__ float sw[OUTC][28];
    __shared__ float sw2[OUTC];

    const int tid = threadIdx.x;

    for (int i = tid; i < OUTC * 25; i += 256) {
        sw[i / 25][i % 25] = wgt[i];
    }
    __syncthreads();
    if (tid < OUTC) {
        float s = 0.f;
        #pragma unroll
        for (int d = 0; d < 25; ++d) { float v = sw[tid][d]; s = fmaf(v, v, s); }
        sw2[tid] = s;
    }
    __syncthreads();

    // Each thread owns 4 consecutive positions in one row (4 | 224, so a
    // group never crosses a row). Block covers 1024 consecutive positions.
    const int g   = blockIdx.x * 256 + tid;   // group index, 0 .. B*L/4-1
    const int b   = g / GPB;
    const int gr  = g - b * GPB;
    const int rem = gr * 4;                   // first of 4 positions
    const int h   = rem / WW;
    const int w0  = rem - h * WW;             // multiple of 4

    const float* xb = x + (size_t)b * LL;

    // 5x8 patch covering columns w0-2 .. w0+5 (all 4 positions' taps).
    // Branchless: clamp address into bounds (always-valid load), mask to 0.
    int  xc[8];
    bool okc[8];
    #pragma unroll
    for (int c = 0; c < 8; ++c) {
        const int xx = w0 + c - PADP;
        xc[c]  = min(max(xx, 0), WW - 1);
        okc[c] = (unsigned)xx < (unsigned)WW;
    }

    float p[5][8];
    #pragma unroll
    for (int r = 0; r < KK; ++r) {
        const int  yy  = h + r - PADP;
        const int  yc  = min(max(yy, 0), HH - 1);
        const bool okr = (unsigned)yy < (unsigned)HH;
        const float* xrow = xb + yc * WW;
        #pragma unroll
        for (int c = 0; c < 8; ++c) {
            float v = xrow[xc[c]];
            p[r][c] = (okr && okc[c]) ? v : 0.f;
        }
    }

    // |x|^2 per position (25 taps each, shared p[][])
    float x2[4];
    #pragma unroll
    for (int j = 0; j < 4; ++j) {
        float s = 0.f;
        #pragma unroll
        for (int r = 0; r < KK; ++r)
            #pragma unroll
            for (int k = 0; k < KK; ++k) {
                const float v = p[r][j + k];
                s = fmaf(v, v, s);
            }
        x2[j] = s;
    }

    float* ob = out + (size_t)b * OUTC * LL + rem;

    for (int o = 0; o < OUTC; ++o) {
        // One broadcast row-read per o, reused by 4 positions.
        float wv[25];
        #pragma unroll
        for (int d = 0; d < 25; ++d) wv[d] = sw[o][d];
        const float w2 = sw2[o];

        // 4 independent 25-FMA dot chains -> ILP covers FMA + LDS latency.
        float dot[4];
        #pragma unroll
        for (int j = 0; j < 4; ++j) {
            float s = 0.f;
            #pragma unroll
            for (int r = 0; r < KK; ++r)
                #pragma unroll
                for (int k = 0; k < KK; ++k)
                    s = fmaf(p[r][j + k], wv[r * KK + k], s);
            dot[j] = s;
        }

        float r4[4];
        #pragma unroll
        for (int j = 0; j < 4; ++j) {
            float d2 = fmaf(-2.f, dot[j], x2[j] + w2);
            d2 = fmaxf(d2, 0.f);
            r4[j] = __builtin_amdgcn_sqrtf(d2);
        }
        // rem is a multiple of 4 and LL is a multiple of 4 -> 16B-aligned.
        *reinterpret_cast<float4*>(ob + (size_t)o * LL) =
            make_float4(r4[0], r4[1], r4[2], r4[3]);
    }
}

extern "C" void kernel_launch(void* const* d_in, const int* in_sizes, int n_in,
                              void* d_out, int out_size, void* d_ws, size_t ws_size,
                              hipStream_t stream) {
    const float* x   = (const float*)d_in[0];
    const float* wgt = (const float*)d_in[1];
    float* out       = (float*)d_out;

    const int groups = BB * GPB;                // 401,408 4-position groups
    const int blocks = groups / 256;            // 1568 blocks
    gray_conv_kernel<<<dim3(blocks), dim3(256), 0, stream>>>(x, wgt, out);
}